// Round 5
// baseline (193.626 us; speedup 1.0000x reference)
//
#include <hip/hip_runtime.h>
#include <math.h>

#define B_ 8
#define N_ 2048
#define H_ 256

// Kernel A: s[m] = sum_o w2[o] * silu( dot(h[m,:], W1[o,:]) + b1[o] ), all f64.
// 16 rows/block (grid 1024 = 4 blocks/CU), 256 threads (4 waves), wave owns
// 4 rows, lane owns 4 o's. h tile in LDS as f64 (32 KB).
// __launch_bounds__(256,2): empirically gives the allocator a 128+ VGPR
// budget (round 2). Bare (256) or (256,4) produced 52 VGPR = spilled
// accumulators = 1.8x slower (rounds 3/4).
__global__ __launch_bounds__(256, 2)
void s_kernel(const float* __restrict__ hp, const float* __restrict__ W1,
              const float* __restrict__ b1, const float* __restrict__ w2,
              double* __restrict__ s_out) {
    __shared__ double hs[16][H_];   // 32 KB
    const int t = threadIdx.x;
    const int m0 = blockIdx.x * 16;

    // Stage 16 rows of h into LDS as f64 (coalesced f32 loads).
    #pragma unroll
    for (int i = 0; i < 16; ++i) {
        hs[i][t] = (double)hp[(size_t)(m0 + i) * H_ + t];
    }
    __syncthreads();

    const int lane = t & 63;
    const int wave = t >> 6;
    const int r0 = wave * 4;    // rows r0..r0+3 of the tile
    const int ob = lane * 4;    // this lane's 4 output columns (o)

    double acc[4][4];
    #pragma unroll
    for (int j = 0; j < 4; ++j)
        #pragma unroll
        for (int r = 0; r < 4; ++r) acc[j][r] = 0.0;

    for (int kc = 0; kc < H_; kc += 8) {
        // W1 chunk for this lane's 4 o-rows: 4 x 8 f32 (two float4 each),
        // 8 kk of FMA work per load batch (round-2 amortization).
        float wreg[4][8];
        #pragma unroll
        for (int j = 0; j < 4; ++j) {
            const float* p = W1 + (size_t)(ob + j) * H_ + kc;
            float4 a = *reinterpret_cast<const float4*>(p);
            float4 b = *reinterpret_cast<const float4*>(p + 4);
            wreg[j][0] = a.x; wreg[j][1] = a.y; wreg[j][2] = a.z; wreg[j][3] = a.w;
            wreg[j][4] = b.x; wreg[j][5] = b.y; wreg[j][6] = b.z; wreg[j][7] = b.w;
        }
        #pragma unroll
        for (int kk = 0; kk < 8; ++kk) {
            double hv[4];
            #pragma unroll
            for (int r = 0; r < 4; ++r) hv[r] = hs[r0 + r][kc + kk];  // broadcast
            #pragma unroll
            for (int j = 0; j < 4; ++j) {
                const double w = (double)wreg[j][kk];
                #pragma unroll
                for (int r = 0; r < 4; ++r) acc[j][r] = fma(w, hv[r], acc[j][r]);
            }
        }
    }

    // Epilogue: bias + silu + dot with w2 (per-lane partial over its 4 o's).
    double spart[4];
    #pragma unroll
    for (int r = 0; r < 4; ++r) spart[r] = 0.0;
    #pragma unroll
    for (int j = 0; j < 4; ++j) {
        const int o = ob + j;
        const double bb = (double)b1[o];
        const double ww = (double)w2[o];
        #pragma unroll
        for (int r = 0; r < 4; ++r) {
            const double u = acc[j][r] + bb;
            const double x = u / (1.0 + exp(-u));   // silu in f64
            spart[r] += ww * x;
        }
    }

    // Wave-level reduction over the 64 lanes (all 256 o's).
    #pragma unroll
    for (int r = 0; r < 4; ++r) {
        double v = spart[r];
        for (int off = 32; off > 0; off >>= 1)
            v += __shfl_down(v, off, 64);
        if (lane == 0) s_out[m0 + r0 + r] = v;
    }
}

// Kernel B: out[b,i,j] = (int32)trunc( (s[b,i] - s[b,j]) + b2 )
// Harness reads integer-dtype outputs as int32 — store int32.
__global__ __launch_bounds__(256)
void pair_kernel(const double* __restrict__ s, const float* __restrict__ b2p,
                 int* __restrict__ out) {
    const double b2 = (double)b2p[0];
    const unsigned total4 = (unsigned)(B_) * (unsigned)(N_) * (unsigned)(N_) / 4u;
    const unsigned stride = gridDim.x * blockDim.x;
    for (unsigned idx = blockIdx.x * blockDim.x + threadIdx.x; idx < total4;
         idx += stride) {
        const unsigned base = idx * 4u;                 // element index, %4==0
        const unsigned bi  = base >> 22;                // / (N*N), N*N = 2^22
        const unsigned rem = base & ((1u << 22) - 1u);
        const unsigned i   = rem >> 11;                 // / N
        const unsigned j   = rem & (N_ - 1u);
        const double si = s[bi * N_ + i];
        const double* sp = s + bi * N_ + j;             // 32B aligned (j%4==0)
        const double sj0 = sp[0], sj1 = sp[1], sj2 = sp[2], sj3 = sp[3];
        int4 o;
        o.x = (int)trunc((si - sj0) + b2);
        o.y = (int)trunc((si - sj1) + b2);
        o.z = (int)trunc((si - sj2) + b2);
        o.w = (int)trunc((si - sj3) + b2);
        *reinterpret_cast<int4*>(out + base) = o;
    }
}

extern "C" void kernel_launch(void* const* d_in, const int* in_sizes, int n_in,
                              void* d_out, int out_size, void* d_ws, size_t ws_size,
                              hipStream_t stream) {
    const float* hp = (const float*)d_in[0];
    // d_in[1] = node_mask (unused by the reference math)
    // d_in[2] = n_nodes   (unused)
    const float* W1 = (const float*)d_in[3];
    const float* b1 = (const float*)d_in[4];
    const float* w2 = (const float*)d_in[5];
    const float* b2 = (const float*)d_in[6];
    double* s  = (double*)d_ws;          // 16384 doubles = 128 KB scratch
    int* out = (int*)d_out;

    s_kernel<<<(B_ * N_) / 16, 256, 0, stream>>>(hp, W1, b1, w2, s);
    pair_kernel<<<2048, 256, 0, stream>>>(s, b2, out);
}

// Round 7
// 95.877 us; speedup vs baseline: 2.0195x; 2.0195x over previous
//
#include <hip/hip_runtime.h>
#include <math.h>

#define B_ 8
#define N_ 2048
#define H_ 256

// Kernel A: s[m] = sum_o w2[o] * silu( dot(h[m,:], W1[o,:]) + b1[o] ), all f64.
// Tile = 16 m-rows, block = 256 threads = 4 waves.
// Wave (rg, oh) = (wave>>1, wave&1): rows rg*8..+8, o-half oh*128..+128.
// Lane owns 2 o's (o = oh*128 + lane*2 + {0,1}) -> acc[2][8] = 32 VGPR.
// h tile f64 in LDS (32 KB); W1 ping-pong register prefetch (one 8-k chunk
// ahead). amdgpu_waves_per_eu(2,4): stops the allocator from chasing 8
// waves/EU occupancy and sinking the f64 accumulators (the 52-VGPR disaster
// of rounds 3-5 with 32 KB LDS).
__global__ __launch_bounds__(256)
__attribute__((amdgpu_waves_per_eu(2, 4)))
void s_kernel(const float* __restrict__ hp, const float* __restrict__ W1,
              const float* __restrict__ b1, const float* __restrict__ w2,
              double* __restrict__ s_out) {
    __shared__ double hs[16][H_];     // 32 KB
    __shared__ double spart[4][8];

    const int t = threadIdx.x;
    const int m0 = blockIdx.x * 16;

    // Stage 16 rows of h into LDS as f64 (coalesced f32 loads, one-time cvt).
    #pragma unroll
    for (int i = 0; i < 16; ++i)
        hs[i][t] = (double)hp[(size_t)(m0 + i) * H_ + t];
    __syncthreads();

    const int lane = t & 63;
    const int wave = t >> 6;
    const int rg = wave >> 1;        // row group (0/1)
    const int oh = wave & 1;         // o half (0/1)
    const int r0 = rg * 8;
    const int o0 = oh * 128 + lane * 2;   // this lane's 2 o's: o0, o0+1

    const float* wp0 = W1 + (size_t)o0 * H_;
    const float* wp1 = W1 + (size_t)(o0 + 1) * H_;

    double acc[2][8];
    #pragma unroll
    for (int j = 0; j < 2; ++j)
        #pragma unroll
        for (int r = 0; r < 8; ++r) acc[j][r] = 0.0;

    float wa[2][8], wb[2][8];   // ping-pong W1 chunks (8 k each)

    // load chunk kc=0 into wa
    #pragma unroll
    for (int j = 0; j < 2; ++j) {
        const float* p = (j == 0 ? wp0 : wp1);
        float4 x = *reinterpret_cast<const float4*>(p);
        float4 y = *reinterpret_cast<const float4*>(p + 4);
        wa[j][0]=x.x; wa[j][1]=x.y; wa[j][2]=x.z; wa[j][3]=x.w;
        wa[j][4]=y.x; wa[j][5]=y.y; wa[j][6]=y.z; wa[j][7]=y.w;
    }

    #define LOADW(dst, kcv)                                                  \
        do {                                                                 \
            _Pragma("unroll")                                                \
            for (int j = 0; j < 2; ++j) {                                    \
                const float* p = (j == 0 ? wp0 : wp1) + (kcv);               \
                float4 x = *reinterpret_cast<const float4*>(p);              \
                float4 y = *reinterpret_cast<const float4*>(p + 4);          \
                dst[j][0]=x.x; dst[j][1]=x.y; dst[j][2]=x.z; dst[j][3]=x.w;  \
                dst[j][4]=y.x; dst[j][5]=y.y; dst[j][6]=y.z; dst[j][7]=y.w;  \
            }                                                                \
        } while (0)

    #define COMPUTE(w)                                                       \
        do {                                                                 \
            _Pragma("unroll")                                                \
            for (int kk = 0; kk < 8; kk += 2) {                              \
                double2 hv[8];                                               \
                _Pragma("unroll")                                            \
                for (int r = 0; r < 8; ++r)                                  \
                    hv[r] = *reinterpret_cast<const double2*>(               \
                        &hs[r0 + r][kc + kk]);   /* uniform: broadcast */    \
                _Pragma("unroll")                                            \
                for (int j = 0; j < 2; ++j) {                                \
                    const double w0 = (double)w[j][kk];                      \
                    const double w1 = (double)w[j][kk + 1];                  \
                    _Pragma("unroll")                                        \
                    for (int r = 0; r < 8; ++r) {                            \
                        acc[j][r] = fma(w0, hv[r].x, acc[j][r]);             \
                        acc[j][r] = fma(w1, hv[r].y, acc[j][r]);             \
                    }                                                        \
                }                                                            \
            }                                                                \
        } while (0)

    // Main loop: 2 chunks per iteration, ping-pong wa/wb (all static indexing).
    for (int kc2 = 0; kc2 < H_; kc2 += 16) {
        {
            const int kc = kc2;
            LOADW(wb, kc2 + 8);           // prefetch next chunk
            COMPUTE(wa);                   // compute current (512cy FMA window)
        }
        {
            const int kc = kc2 + 8;
            if (kc2 + 16 < H_) LOADW(wa, kc2 + 16);
            COMPUTE(wb);
        }
    }
    #undef LOADW
    #undef COMPUTE

    // Epilogue: bias + silu + w2-dot over this lane's 2 o's.
    double psum[8];
    #pragma unroll
    for (int r = 0; r < 8; ++r) psum[r] = 0.0;
    #pragma unroll
    for (int j = 0; j < 2; ++j) {
        const int o = o0 + j;
        const double bb = (double)b1[o];
        const double ww = (double)w2[o];
        #pragma unroll
        for (int r = 0; r < 8; ++r) {
            const double u = acc[j][r] + bb;
            psum[r] += ww * (u / (1.0 + exp(-u)));   // silu in f64
        }
    }

    // Reduce over the wave's 64 lanes (covers this o-half, 128 o's).
    #pragma unroll
    for (int r = 0; r < 8; ++r) {
        double v = psum[r];
        v += __shfl_xor(v, 1, 64);
        v += __shfl_xor(v, 2, 64);
        v += __shfl_xor(v, 4, 64);
        v += __shfl_xor(v, 8, 64);
        v += __shfl_xor(v, 16, 64);
        v += __shfl_xor(v, 32, 64);
        psum[r] = v;
    }
    if (lane == 0) {
        #pragma unroll
        for (int r = 0; r < 8; ++r) spart[wave][r] = psum[r];
    }
    __syncthreads();

    // Combine the two o-halves per row; rows = rg*8 + r = t for t<16.
    if (t < 16) {
        const int rgf = t >> 3, rf = t & 7;
        s_out[m0 + t] = spart[rgf * 2 + 0][rf] + spart[rgf * 2 + 1][rf];
    }
}

// Kernel B: out[b,i,j] = (int32)trunc( (s[b,i] - s[b,j]) + b2 )
__global__ __launch_bounds__(256)
void pair_kernel(const double* __restrict__ s, const float* __restrict__ b2p,
                 int* __restrict__ out) {
    const double b2 = (double)b2p[0];
    const unsigned total4 = (unsigned)(B_) * (unsigned)(N_) * (unsigned)(N_) / 4u;
    const unsigned stride = gridDim.x * blockDim.x;
    for (unsigned idx = blockIdx.x * blockDim.x + threadIdx.x; idx < total4;
         idx += stride) {
        const unsigned base = idx * 4u;                 // element index, %4==0
        const unsigned bi  = base >> 22;                // / (N*N), N*N = 2^22
        const unsigned rem = base & ((1u << 22) - 1u);
        const unsigned i   = rem >> 11;                 // / N
        const unsigned j   = rem & (N_ - 1u);
        const double si = s[bi * N_ + i];
        const double* sp = s + bi * N_ + j;             // 32B aligned (j%4==0)
        const double sj0 = sp[0], sj1 = sp[1], sj2 = sp[2], sj3 = sp[3];
        int4 o;
        o.x = (int)trunc((si - sj0) + b2);
        o.y = (int)trunc((si - sj1) + b2);
        o.z = (int)trunc((si - sj2) + b2);
        o.w = (int)trunc((si - sj3) + b2);
        *reinterpret_cast<int4*>(out + base) = o;
    }
}

extern "C" void kernel_launch(void* const* d_in, const int* in_sizes, int n_in,
                              void* d_out, int out_size, void* d_ws, size_t ws_size,
                              hipStream_t stream) {
    const float* hp = (const float*)d_in[0];
    // d_in[1] = node_mask (unused), d_in[2] = n_nodes (unused)
    const float* W1 = (const float*)d_in[3];
    const float* b1 = (const float*)d_in[4];
    const float* w2 = (const float*)d_in[5];
    const float* b2 = (const float*)d_in[6];
    double* s  = (double*)d_ws;          // 16384 doubles = 128 KB scratch
    int* out = (int*)d_out;

    s_kernel<<<(B_ * N_) / 16, 256, 0, stream>>>(hp, W1, b1, w2, s);
    pair_kernel<<<2048, 256, 0, stream>>>(s, b2, out);
}

// Round 8
// 90.934 us; speedup vs baseline: 2.1293x; 1.0544x over previous
//
#include <hip/hip_runtime.h>
#include <math.h>

#define B_ 8
#define N_ 2048
#define H_ 256

// One-shot: W1T[k][o] = W1[o][k] (f32, 256 KB in d_ws). Makes the s_kernel
// W1 reads unit-stride across lanes (round 7 was pulling >=4x over-fetch
// through L2: each lane read float4 from its own 1KB-apart row -> 64 lines
// per wave-load, 16B used per 64B line).
__global__ __launch_bounds__(256)
void transpose_w1(const float* __restrict__ W1, float* __restrict__ W1T) {
    W1T[(size_t)blockIdx.x * H_ + threadIdx.x] =
        W1[(size_t)threadIdx.x * H_ + blockIdx.x];
}

// Kernel A: s[m] = sum_o w2[o] * silu( dot(h[m,:], W1[o,:]) + b1[o] ), f64.
// Tile = 16 m-rows, block = 256 threads = 4 waves.
// Wave (rg, oh): rows rg*8..+8, o-half oh*128..+128.
// Lane owns o0 = oh*128 + 2*lane and o0+1 -> one coalesced float2 per k.
// h tile f64 in LDS (broadcast reads); W1T ping-pong register prefetch.
// amdgpu_waves_per_eu(2,4): keeps the allocator at a 128-VGPR budget
// (bare bounds gave 52 VGPR = spilled accumulators, rounds 3-5).
__global__ __launch_bounds__(256)
__attribute__((amdgpu_waves_per_eu(2, 4)))
void s_kernel(const float* __restrict__ hp, const float* __restrict__ W1T,
              const float* __restrict__ b1, const float* __restrict__ w2,
              double* __restrict__ s_out) {
    __shared__ double hs[16][H_];     // 32 KB
    __shared__ double spart[4][8];

    const int t = threadIdx.x;
    const int m0 = blockIdx.x * 16;

    // Stage 16 rows of h into LDS as f64 (coalesced f32 loads).
    #pragma unroll
    for (int i = 0; i < 16; ++i)
        hs[i][t] = (double)hp[(size_t)(m0 + i) * H_ + t];
    __syncthreads();

    const int lane = t & 63;
    const int wave = t >> 6;
    const int rg = wave >> 1;        // row group (0/1)
    const int oh = wave & 1;         // o half (0/1)
    const int r0 = rg * 8;
    const int o0 = oh * 128 + lane * 2;   // this lane's o's: o0, o0+1

    const float* wt = W1T + o0;      // row k: wt + k*H_ (unit-stride in lanes)

    double acc[2][8];
    #pragma unroll
    for (int j = 0; j < 2; ++j)
        #pragma unroll
        for (int r = 0; r < 8; ++r) acc[j][r] = 0.0;

    float2 wa[8], wb[8];   // ping-pong W1T chunks (8 k each, both o's packed)

    #define LOADW(dst, kcv)                                                   \
        do {                                                                  \
            _Pragma("unroll")                                                 \
            for (int kk = 0; kk < 8; ++kk)                                    \
                dst[kk] = *reinterpret_cast<const float2*>(                   \
                    wt + (size_t)((kcv) + kk) * H_);                          \
        } while (0)

    #define COMPUTE(w, kc)                                                    \
        do {                                                                  \
            _Pragma("unroll")                                                 \
            for (int kk = 0; kk < 8; kk += 2) {                               \
                double2 hv[8];                                                \
                _Pragma("unroll")                                             \
                for (int r = 0; r < 8; ++r)                                   \
                    hv[r] = *reinterpret_cast<const double2*>(                \
                        &hs[r0 + r][(kc) + kk]);  /* uniform: broadcast */    \
                const double w00 = (double)w[kk].x;     /* o0, k   */         \
                const double w01 = (double)w[kk].y;     /* o1, k   */         \
                const double w10 = (double)w[kk + 1].x; /* o0, k+1 */         \
                const double w11 = (double)w[kk + 1].y; /* o1, k+1 */         \
                _Pragma("unroll")                                             \
                for (int r = 0; r < 8; ++r) {                                 \
                    acc[0][r] = fma(w00, hv[r].x, acc[0][r]);                 \
                    acc[0][r] = fma(w10, hv[r].y, acc[0][r]);                 \
                    acc[1][r] = fma(w01, hv[r].x, acc[1][r]);                 \
                    acc[1][r] = fma(w11, hv[r].y, acc[1][r]);                 \
                }                                                             \
            }                                                                 \
        } while (0)

    LOADW(wa, 0);
    for (int kc2 = 0; kc2 < H_; kc2 += 16) {
        LOADW(wb, kc2 + 8);                 // prefetch next chunk
        COMPUTE(wa, kc2);                   // ~512cy FMA window covers it
        if (kc2 + 16 < H_) LOADW(wa, kc2 + 16);
        COMPUTE(wb, kc2 + 8);
    }
    #undef LOADW
    #undef COMPUTE

    // Epilogue: bias + silu + w2-dot over this lane's 2 o's.
    double psum[8];
    #pragma unroll
    for (int r = 0; r < 8; ++r) psum[r] = 0.0;
    #pragma unroll
    for (int j = 0; j < 2; ++j) {
        const int o = o0 + j;
        const double bb = (double)b1[o];
        const double ww = (double)w2[o];
        #pragma unroll
        for (int r = 0; r < 8; ++r) {
            const double u = acc[j][r] + bb;
            psum[r] += ww * (u / (1.0 + exp(-u)));   // silu in f64
        }
    }

    // Reduce over the wave's 64 lanes (covers this o-half, 128 o's).
    #pragma unroll
    for (int r = 0; r < 8; ++r) {
        double v = psum[r];
        v += __shfl_xor(v, 1, 64);
        v += __shfl_xor(v, 2, 64);
        v += __shfl_xor(v, 4, 64);
        v += __shfl_xor(v, 8, 64);
        v += __shfl_xor(v, 16, 64);
        v += __shfl_xor(v, 32, 64);
        psum[r] = v;
    }
    if (lane == 0) {
        #pragma unroll
        for (int r = 0; r < 8; ++r) spart[wave][r] = psum[r];
    }
    __syncthreads();

    // Combine the two o-halves per row; rows = rg*8 + r = t for t<16.
    if (t < 16) {
        const int rgf = t >> 3, rf = t & 7;
        s_out[m0 + t] = spart[rgf * 2 + 0][rf] + spart[rgf * 2 + 1][rf];
    }
}

// Kernel B: out[b,i,j] = (int32)trunc( (s[b,i] - s[b,j]) + b2 )
__global__ __launch_bounds__(256)
void pair_kernel(const double* __restrict__ s, const float* __restrict__ b2p,
                 int* __restrict__ out) {
    const double b2 = (double)b2p[0];
    const unsigned total4 = (unsigned)(B_) * (unsigned)(N_) * (unsigned)(N_) / 4u;
    const unsigned stride = gridDim.x * blockDim.x;
    for (unsigned idx = blockIdx.x * blockDim.x + threadIdx.x; idx < total4;
         idx += stride) {
        const unsigned base = idx * 4u;                 // element index, %4==0
        const unsigned bi  = base >> 22;                // / (N*N), N*N = 2^22
        const unsigned rem = base & ((1u << 22) - 1u);
        const unsigned i   = rem >> 11;                 // / N
        const unsigned j   = rem & (N_ - 1u);
        const double si = s[bi * N_ + i];
        const double* sp = s + bi * N_ + j;             // 32B aligned (j%4==0)
        const double sj0 = sp[0], sj1 = sp[1], sj2 = sp[2], sj3 = sp[3];
        int4 o;
        o.x = (int)trunc((si - sj0) + b2);
        o.y = (int)trunc((si - sj1) + b2);
        o.z = (int)trunc((si - sj2) + b2);
        o.w = (int)trunc((si - sj3) + b2);
        *reinterpret_cast<int4*>(out + base) = o;
    }
}

extern "C" void kernel_launch(void* const* d_in, const int* in_sizes, int n_in,
                              void* d_out, int out_size, void* d_ws, size_t ws_size,
                              hipStream_t stream) {
    const float* hp = (const float*)d_in[0];
    // d_in[1] = node_mask (unused), d_in[2] = n_nodes (unused)
    const float* W1 = (const float*)d_in[3];
    const float* b1 = (const float*)d_in[4];
    const float* w2 = (const float*)d_in[5];
    const float* b2 = (const float*)d_in[6];

    float* W1T = (float*)d_ws;                         // 256 KB
    double* s  = (double*)((char*)d_ws + H_ * H_ * sizeof(float)); // 128 KB
    int* out = (int*)d_out;

    transpose_w1<<<H_, H_, 0, stream>>>(W1, W1T);
    s_kernel<<<(B_ * N_) / 16, 256, 0, stream>>>(hp, W1T, b1, w2, s);
    pair_kernel<<<2048, 256, 0, stream>>>(s, b2, out);
}

// Round 9
// 86.843 us; speedup vs baseline: 2.2296x; 1.0471x over previous
//
#include <hip/hip_runtime.h>
#include <math.h>

#define B_ 8
#define N_ 2048
#define H_ 256

// One-shot: W1T[k][o] = W1[o][k] (f32, 256 KB in d_ws) -> unit-stride lane
// reads in s_kernel.
__global__ __launch_bounds__(256)
void transpose_w1(const float* __restrict__ W1, float* __restrict__ W1T) {
    W1T[(size_t)blockIdx.x * H_ + threadIdx.x] =
        W1[(size_t)threadIdx.x * H_ + blockIdx.x];
}

// Kernel A: s[m] = sum_o w2[o] * silu( dot(h[m,:], W1[o,:]) + b1[o] ), f64.
// Tile = 16 m-rows, 4 waves. Wave owns 4 rows (r0 = wave*4) and ALL 256 o.
// Lane owns 4 consecutive o's (o0 = lane*4): one coalesced float4 of W1T
// per k (1 KB/wave-load). Per h double2 (2 k, 1 row): 8 FMAs -> half the
// LDS instr rate of round 8. Both streams software-pipelined:
//   hA/hB: h k-pair from LDS, loaded one pair (32 FMA = 128 cy) ahead.
//   wcur/wnxt: W1T 4-k chunk from global/L2, loaded one chunk (512 cy) ahead.
// amdgpu_waves_per_eu(2,4): keeps allocator off the 52-VGPR spill regime.
__global__ __launch_bounds__(256)
__attribute__((amdgpu_waves_per_eu(2, 4)))
void s_kernel(const float* __restrict__ hp, const float* __restrict__ W1T,
              const float* __restrict__ b1, const float* __restrict__ w2,
              double* __restrict__ s_out) {
    __shared__ double hs[16][H_];     // 32 KB

    const int t = threadIdx.x;
    const int m0 = blockIdx.x * 16;

    // Stage 16 rows of h into LDS as f64 (coalesced f32 loads; 2-way bank
    // alias on write = free).
    #pragma unroll
    for (int i = 0; i < 16; ++i)
        hs[i][t] = (double)hp[(size_t)(m0 + i) * H_ + t];
    __syncthreads();

    const int lane = t & 63;
    const int wave = t >> 6;
    const int r0 = wave * 4;          // this wave's 4 rows
    const int o0 = lane * 4;          // this lane's 4 o's

    const float* wp = W1T + o0;       // row k at wp + k*H_

    double acc[4][4];                 // [o_j][row_r]
    #pragma unroll
    for (int j = 0; j < 4; ++j)
        #pragma unroll
        for (int r = 0; r < 4; ++r) acc[j][r] = 0.0;

    float4 wcur[4], wnxt[4];          // W1T chunk: k = kc..kc+3, lane's 4 o's
    double2 hA[4], hB[4];             // h k-pair for the 4 rows (broadcast)

    #pragma unroll
    for (int kk = 0; kk < 4; ++kk)
        wcur[kk] = *reinterpret_cast<const float4*>(wp + (size_t)kk * H_);
    #pragma unroll
    for (int r = 0; r < 4; ++r)
        hA[r] = *reinterpret_cast<const double2*>(&hs[r0 + r][0]);

    // 32 FMAs on one h k-pair (2 k's x 4 o's x 4 rows), w from two float4.
    #define PAIR(hv, wka, wkb)                                                \
        do {                                                                  \
            const double a0 = (double)wka.x, a1 = (double)wka.y,              \
                         a2 = (double)wka.z, a3 = (double)wka.w;              \
            const double c0 = (double)wkb.x, c1 = (double)wkb.y,              \
                         c2 = (double)wkb.z, c3 = (double)wkb.w;              \
            _Pragma("unroll")                                                 \
            for (int r = 0; r < 4; ++r) {                                     \
                acc[0][r] = fma(a0, hv[r].x, acc[0][r]);                      \
                acc[0][r] = fma(c0, hv[r].y, acc[0][r]);                      \
                acc[1][r] = fma(a1, hv[r].x, acc[1][r]);                      \
                acc[1][r] = fma(c1, hv[r].y, acc[1][r]);                      \
                acc[2][r] = fma(a2, hv[r].x, acc[2][r]);                      \
                acc[2][r] = fma(c2, hv[r].y, acc[2][r]);                      \
                acc[3][r] = fma(a3, hv[r].x, acc[3][r]);                      \
                acc[3][r] = fma(c3, hv[r].y, acc[3][r]);                      \
            }                                                                 \
        } while (0)

    for (int kc = 0; kc < H_; kc += 4) {
        const int kn = (kc + 4 < H_) ? (kc + 4) : 0;   // next chunk (guarded)
        // Prefetch next W chunk (global/L2), one full chunk ahead.
        #pragma unroll
        for (int kk = 0; kk < 4; ++kk)
            wnxt[kk] = *reinterpret_cast<const float4*>(
                wp + (size_t)(kn + kk) * H_);
        // Prefetch h pair (kc+2, kc+3) while computing pair (kc, kc+1).
        #pragma unroll
        for (int r = 0; r < 4; ++r)
            hB[r] = *reinterpret_cast<const double2*>(&hs[r0 + r][kc + 2]);
        PAIR(hA, wcur[0], wcur[1]);
        // Prefetch h pair for the next chunk while computing (kc+2, kc+3).
        #pragma unroll
        for (int r = 0; r < 4; ++r)
            hA[r] = *reinterpret_cast<const double2*>(&hs[r0 + r][kn]);
        PAIR(hB, wcur[2], wcur[3]);
        #pragma unroll
        for (int kk = 0; kk < 4; ++kk) wcur[kk] = wnxt[kk];
    }
    #undef PAIR

    // Epilogue: bias + silu + w2-dot over this lane's 4 o's; psum[r] is the
    // lane's partial of s[m0+r0+r] over o = o0..o0+3.
    const float4 b1v = *reinterpret_cast<const float4*>(b1 + o0);
    const float4 w2v = *reinterpret_cast<const float4*>(w2 + o0);
    double psum[4] = {0.0, 0.0, 0.0, 0.0};
    #define EPI(j, bc, wc)                                                    \
        do {                                                                  \
            const double bb = (double)bc, ww = (double)wc;                    \
            _Pragma("unroll")                                                 \
            for (int r = 0; r < 4; ++r) {                                     \
                const double u = acc[j][r] + bb;                              \
                psum[r] += ww * (u / (1.0 + exp(-u)));                        \
            }                                                                 \
        } while (0)
    EPI(0, b1v.x, w2v.x);
    EPI(1, b1v.y, w2v.y);
    EPI(2, b1v.z, w2v.z);
    EPI(3, b1v.w, w2v.w);
    #undef EPI

    // Full-wave reduce (64 lanes cover all 256 o's); lane 0 writes s.
    #pragma unroll
    for (int r = 0; r < 4; ++r) {
        double v = psum[r];
        v += __shfl_xor(v, 1, 64);
        v += __shfl_xor(v, 2, 64);
        v += __shfl_xor(v, 4, 64);
        v += __shfl_xor(v, 8, 64);
        v += __shfl_xor(v, 16, 64);
        v += __shfl_xor(v, 32, 64);
        if (lane == 0) s_out[m0 + r0 + r] = v;
    }
}

// Kernel B: out[b,i,j] = (int32)trunc( (s[b,i] - s[b,j]) + b2 )
__global__ __launch_bounds__(256)
void pair_kernel(const double* __restrict__ s, const float* __restrict__ b2p,
                 int* __restrict__ out) {
    const double b2 = (double)b2p[0];
    const unsigned total4 = (unsigned)(B_) * (unsigned)(N_) * (unsigned)(N_) / 4u;
    const unsigned stride = gridDim.x * blockDim.x;
    for (unsigned idx = blockIdx.x * blockDim.x + threadIdx.x; idx < total4;
         idx += stride) {
        const unsigned base = idx * 4u;                 // element index, %4==0
        const unsigned bi  = base >> 22;                // / (N*N), N*N = 2^22
        const unsigned rem = base & ((1u << 22) - 1u);
        const unsigned i   = rem >> 11;                 // / N
        const unsigned j   = rem & (N_ - 1u);
        const double si = s[bi * N_ + i];
        const double* sp = s + bi * N_ + j;             // 32B aligned (j%4==0)
        const double sj0 = sp[0], sj1 = sp[1], sj2 = sp[2], sj3 = sp[3];
        int4 o;
        o.x = (int)trunc((si - sj0) + b2);
        o.y = (int)trunc((si - sj1) + b2);
        o.z = (int)trunc((si - sj2) + b2);
        o.w = (int)trunc((si - sj3) + b2);
        *reinterpret_cast<int4*>(out + base) = o;
    }
}

extern "C" void kernel_launch(void* const* d_in, const int* in_sizes, int n_in,
                              void* d_out, int out_size, void* d_ws, size_t ws_size,
                              hipStream_t stream) {
    const float* hp = (const float*)d_in[0];
    // d_in[1] = node_mask (unused), d_in[2] = n_nodes (unused)
    const float* W1 = (const float*)d_in[3];
    const float* b1 = (const float*)d_in[4];
    const float* w2 = (const float*)d_in[5];
    const float* b2 = (const float*)d_in[6];

    float* W1T = (float*)d_ws;                                     // 256 KB
    double* s  = (double*)((char*)d_ws + H_ * H_ * sizeof(float)); // 128 KB
    int* out = (int*)d_out;

    transpose_w1<<<H_, H_, 0, stream>>>(W1, W1T);
    s_kernel<<<(B_ * N_) / 16, 256, 0, stream>>>(hp, W1T, b1, w2, s);
    pair_kernel<<<2048, 256, 0, stream>>>(s, b2, out);
}